// Round 25
// baseline (34.645 us; speedup 1.0000x reference)
//
#include <hip/hip_runtime.h>

// ShiftGraph: B=8, C=16, H=W=256, d=5 (r=2), 24 shifts.
// Output (flat float32): edges (B, E, 2) then ws (B, E), E = 1557540.
// R25: R21 structure (raw barriers, pair symmetry, interleaved edge stores)
// with CHANNEL-CONTIGUOUS LDS [3row][256col][4ch]: one ds_read_b128 fetches
// all 4 channels of a neighbor -> 52 b128 vs 208 b32 (LDS pipe ~16->8 us).
// Staging: 12 scalar global dwords/chunk (4x64B segs/wave, L2-resident),
// lane-consecutive LDS writes (conflict-free).

#define HH 256
#define WW 256
#define CC 16
#define BB 8
#define HW (HH * WW)
#define EE 1557540

__global__ __launch_bounds__(256) void shiftgraph_kernel(
    const float* __restrict__ x, float* __restrict__ out) {
    __shared__ float lds[3072];     // [3row][256col][4ch]
    const int bid = blockIdx.x;
    const int b = bid & 7;          // batch -> XCD
    const int h = bid >> 3;         // row
    const int w = threadIdx.x;      // col (= output pixel)

    const float* __restrict__ xb = x + (size_t)b * (CC * HW);

    // staging: thread w stages ch = w&3 at cols (w>>2)+{0,64,128,192},
    // rows h..h+2 (clamped; clamped values feed only store-guarded lanes).
    // LDS dst dword = row*1024 + colgrp*256 + w  (lane-consecutive).
    const int ch = w & 3;
    const int cq = w >> 2;
    const float* prow[3];
#pragma unroll
    for (int r = 0; r < 3; ++r) {
        int hr = h + r; hr = hr > HH - 1 ? HH - 1 : hr;
        prow[r] = xb + ch * HW + hr * WW + cq;
    }

    // clamped neighbor cols (clamped only where stores are guarded)
    const int wp1 = w + 1 > 255 ? 255 : w + 1;
    const int wp2 = w + 2 > 255 ? 255 : w + 2;
    const int wm1 = w - 1 < 0 ? 0 : w - 1;
    const int wm2 = w - 2 < 0 ? 0 : w - 2;

    float* __restrict__ edges = out;                        // (B, E, 2)
    float* __restrict__ wsp   = out + (size_t)BB * EE * 2;  // (B, E)
    const size_t bE = (size_t)b * EE;
    const int posc = h * WW + w;

    float acc[12];
#pragma unroll
    for (int s2 = 0; s2 < 12; ++s2) acc[s2] = 0.0f;

    const float4* __restrict__ ldsv = reinterpret_cast<const float4*>(lds);

#pragma unroll
    for (int cc = 0; cc < 4; ++cc) {
        if (cc > 0) {
            // WAR: all waves done reading chunk cc-1
            asm volatile("" ::: "memory");
            __builtin_amdgcn_s_barrier();
            __builtin_amdgcn_sched_barrier(0);
        }
        // ---- stage chunk cc (channels 4cc..4cc+3) ----
#pragma unroll
        for (int inst = 0; inst < 12; ++inst) {
            const int r = inst >> 2, k = inst & 3;
            lds[r * 1024 + k * 256 + w] = prow[r][(size_t)cc * 4 * HW + k * 64];
        }
        // RAW: own LDS writes done; NO vmcnt drain (stores stay in flight)
        asm volatile("s_waitcnt lgkmcnt(0)" ::: "memory");
        __builtin_amdgcn_s_barrier();
        __builtin_amdgcn_sched_barrier(0);

        // ---- compute: 13 x ds_read_b128 ----
        {
            const float4 ctr = ldsv[w];                       // row 0, own col
            float4 nb; float dx, dy, dz, dw_;
#define ACCUM(IDX, SLOT)                                                   \
            nb = ldsv[IDX];                                                \
            dx = nb.x - ctr.x; dy = nb.y - ctr.y;                          \
            dz = nb.z - ctr.z; dw_ = nb.w - ctr.w;                         \
            acc[SLOT] = fmaf(dx, dx, acc[SLOT]);                           \
            acc[SLOT] = fmaf(dy, dy, acc[SLOT]);                           \
            acc[SLOT] = fmaf(dz, dz, acc[SLOT]);                           \
            acc[SLOT] = fmaf(dw_, dw_, acc[SLOT]);
            ACCUM(wp1, 0)            // (0,+1)
            ACCUM(wp2, 1)            // (0,+2)
            ACCUM(256 + wm2, 2)      // (1,-2)
            ACCUM(256 + wm1, 3)      // (1,-1)
            ACCUM(256 + w,   4)      // (1, 0)
            ACCUM(256 + wp1, 5)      // (1,+1)
            ACCUM(256 + wp2, 6)      // (1,+2)
            ACCUM(512 + wm2, 7)      // (2,-2)
            ACCUM(512 + wm1, 8)      // (2,-1)
            ACCUM(512 + w,   9)      // (2, 0)
            ACCUM(512 + wp1, 10)     // (2,+1)
            ACCUM(512 + wp2, 11)     // (2,+2)
#undef ACCUM
        }

        // ---- edge stores for shifts 3cc..3cc+2 (x-independent) ----
        {
            int s = 0;
#pragma unroll
            for (int di = 0; di <= 2; ++di) {
#pragma unroll
                for (int dj = (di == 0 ? 1 : -2); dj <= 2; ++dj, ++s) {
                    if (s < cc * 3 || s >= cc * 3 + 3) continue;  // compile-time
                    const int i = di + 2, j = dj + 2;
                    if (h + di >= HH) continue;          // wave-uniform
                    const int w2 = w + dj;
                    if (w2 < 0 || w2 >= WW) continue;    // <=2 edge lanes

                    int offF = 0, offM = 0;              // compile-time prefixes
#pragma unroll
                    for (int m = 0; m < 25; ++m) {
                        const int mi = m / 5, mj = m % 5;
                        if (mi == 2 && mj == 2) continue;
                        const int cm = (HH - (mi < 2 ? 2 - mi : mi - 2)) *
                                       (WW - (mj < 2 ? 2 - mj : mj - 2));
                        if (m < i * 5 + j) offF += cm;
                        if (m < (4 - i) * 5 + (4 - j)) offM += cm;
                    }
                    const int cww = WW - (dj < 0 ? -dj : dj);
                    const int e1 = offF + h * cww + (w - (dj < 0 ? -dj : 0));
                    const int e2 = offM + h * cww + (w + (dj < 0 ? dj : 0));
                    const int posv = di * WW + dj;

                    *reinterpret_cast<float2*>(edges + (bE + e1) * 2) =
                        make_float2((float)posc, (float)(posc + posv));
                    *reinterpret_cast<float2*>(edges + (bE + e2) * 2) =
                        make_float2((float)(posc + posv), (float)posc);
                }
            }
        }
    }

    // ---- ws stores (own + mirror) ----
    {
        int s = 0;
#pragma unroll
        for (int di = 0; di <= 2; ++di) {
#pragma unroll
            for (int dj = (di == 0 ? 1 : -2); dj <= 2; ++dj, ++s) {
                const int i = di + 2, j = dj + 2;
                if (h + di >= HH) continue;              // wave-uniform
                const int w2 = w + dj;
                if (w2 < 0 || w2 >= WW) continue;        // <=2 edge lanes

                const float scale = sqrtf((float)(di * di + dj * dj));
                const float wsv = -acc[s] * scale;

                int offF = 0, offM = 0;                  // compile-time prefixes
#pragma unroll
                for (int m = 0; m < 25; ++m) {
                    const int mi = m / 5, mj = m % 5;
                    if (mi == 2 && mj == 2) continue;
                    const int cm = (HH - (mi < 2 ? 2 - mi : mi - 2)) *
                                   (WW - (mj < 2 ? 2 - mj : mj - 2));
                    if (m < i * 5 + j) offF += cm;
                    if (m < (4 - i) * 5 + (4 - j)) offM += cm;
                }
                const int cww = WW - (dj < 0 ? -dj : dj);
                const int e1 = offF + h * cww + (w - (dj < 0 ? -dj : 0));
                const int e2 = offM + h * cww + (w + (dj < 0 ? dj : 0));

                wsp[bE + e1] = wsv;
                wsp[bE + e2] = wsv;
            }
        }
    }
}

extern "C" void kernel_launch(void* const* d_in, const int* in_sizes, int n_in,
                              void* d_out, int out_size, void* d_ws, size_t ws_size,
                              hipStream_t stream) {
    const float* x = (const float*)d_in[0];
    float* out = (float*)d_out;
    dim3 block(WW);            // one thread per column
    dim3 grid(HH * BB);        // one block per (row, batch)
    shiftgraph_kernel<<<grid, block, 0, stream>>>(x, out);
}

// Round 26
// 32.875 us; speedup vs baseline: 1.0538x; 1.0538x over previous
//
#include <hip/hip_runtime.h>

// ShiftGraph: B=8, C=16, H=W=256, d=5 (r=2), 24 shifts.
// Output (flat float32): edges (B, E, 2) then ws (B, E), E = 1557540.
// R26 = R21 (session best, 32.9 us): R18 core (block-cooperative LDS staging
// in 4-ch chunks, pair symmetry, 2048x256, plain stores) + raw s_barrier/
// lgkmcnt barriers (NO vmcnt drain) + edge stores (x-independent, 100MB)
// interleaved 3 shifts per chunk. ws stores at end.
// Ablation ledger (R14-R25): store drain ~21.6us at fill rate + ~11us
// unhideable head; every single-component ablation neutral -> practical
// plateau ~33us (5.1 TB/s effective, 81% of copy ceiling on 90/10 mix).

#define HH 256
#define WW 256
#define CC 16
#define BB 8
#define HW (HH * WW)
#define EE 1557540

__global__ __launch_bounds__(256) void shiftgraph_kernel(
    const float* __restrict__ x, float* __restrict__ out) {
    __shared__ float lds[3080];     // [4ch][3rows][256cols] + pad
    const int bid = blockIdx.x;
    const int b = bid & 7;          // batch -> XCD
    const int h = bid >> 3;         // row
    const int w = threadIdx.x;      // col

    const float* __restrict__ xb = x + (size_t)b * (CC * HW);

    // staging map (R16/R18-proven): 3072 floats = [cl][row][col]
    const float* src[3];
    int dst[3];
#pragma unroll
    for (int inst = 0; inst < 3; ++inst) {
        const int flatf = inst * 1024 + w * 4;
        const int cl  = flatf / 768;
        const int rem = flatf - cl * 768;
        const int row = rem >> 8;
        const int col = rem & 255;
        int hr = h + row; hr = hr > HH - 1 ? HH - 1 : hr;  // clamp: guarded
        src[inst] = xb + cl * HW + hr * WW + col;
        dst[inst] = flatf;
    }

    float* __restrict__ edges = out;                        // (B, E, 2)
    float* __restrict__ wsp   = out + (size_t)BB * EE * 2;  // (B, E)
    const size_t bE = (size_t)b * EE;
    const int posc = h * WW + w;

    float acc[12];
#pragma unroll
    for (int s2 = 0; s2 < 12; ++s2) acc[s2] = 0.0f;

#pragma unroll
    for (int cc = 0; cc < 4; ++cc) {
        if (cc > 0) {
            // WAR: all waves done reading chunk cc-1 (reads consumed pre-arrival)
            asm volatile("" ::: "memory");
            __builtin_amdgcn_s_barrier();
            __builtin_amdgcn_sched_barrier(0);
        }
#pragma unroll
        for (int inst = 0; inst < 3; ++inst) {
            const float4 v = *reinterpret_cast<const float4*>(src[inst]);
            *reinterpret_cast<float4*>(&lds[dst[inst]]) = v;
            src[inst] += 4 * HW;
        }
        // RAW: own LDS writes complete before arrival; NO vmcnt drain
        asm volatile("s_waitcnt lgkmcnt(0)" ::: "memory");
        __builtin_amdgcn_s_barrier();
        __builtin_amdgcn_sched_barrier(0);

#pragma unroll
        for (int c = 0; c < 4; ++c) {
            const int base = c * 768 + w;   // addr = w*4 + compile-time imm
            const float ctr = lds[base];
            float d;
            d = lds[base + 1] - ctr; acc[0] = fmaf(d, d, acc[0]);   // (0,1)
            d = lds[base + 2] - ctr; acc[1] = fmaf(d, d, acc[1]);   // (0,2)
#pragma unroll
            for (int dj = -2; dj <= 2; ++dj) {
                d = lds[base + 256 + dj] - ctr;                     // (1,dj)
                acc[4 + dj] = fmaf(d, d, acc[4 + dj]);
                d = lds[base + 512 + dj] - ctr;                     // (2,dj)
                acc[9 + dj] = fmaf(d, d, acc[9 + dj]);
            }
        }

        // ---- edge stores for shifts 3cc..3cc+2 (x-independent; stores
        // stay in flight across the raw barriers) ----
        {
            int s = 0;
#pragma unroll
            for (int di = 0; di <= 2; ++di) {
#pragma unroll
                for (int dj = (di == 0 ? 1 : -2); dj <= 2; ++dj, ++s) {
                    if (s < cc * 3 || s >= cc * 3 + 3) continue;  // compile-time
                    const int i = di + 2, j = dj + 2;
                    if (h + di >= HH) continue;          // wave-uniform
                    const int w2 = w + dj;
                    if (w2 < 0 || w2 >= WW) continue;    // <=2 edge lanes

                    int offF = 0, offM = 0;              // compile-time prefixes
#pragma unroll
                    for (int m = 0; m < 25; ++m) {
                        const int mi = m / 5, mj = m % 5;
                        if (mi == 2 && mj == 2) continue;
                        const int cm = (HH - (mi < 2 ? 2 - mi : mi - 2)) *
                                       (WW - (mj < 2 ? 2 - mj : mj - 2));
                        if (m < i * 5 + j) offF += cm;
                        if (m < (4 - i) * 5 + (4 - j)) offM += cm;
                    }
                    const int cww = WW - (dj < 0 ? -dj : dj);
                    const int e1 = offF + h * cww + (w - (dj < 0 ? -dj : 0));
                    const int e2 = offM + h * cww + (w + (dj < 0 ? dj : 0));
                    const int posv = di * WW + dj;

                    *reinterpret_cast<float2*>(edges + (bE + e1) * 2) =
                        make_float2((float)posc, (float)(posc + posv));
                    *reinterpret_cast<float2*>(edges + (bE + e2) * 2) =
                        make_float2((float)(posc + posv), (float)posc);
                }
            }
        }
    }

    // ---- ws stores (own + mirror) ----
    int s = 0;
#pragma unroll
    for (int di = 0; di <= 2; ++di) {
#pragma unroll
        for (int dj = (di == 0 ? 1 : -2); dj <= 2; ++dj, ++s) {
            const int i = di + 2, j = dj + 2;
            if (h + di >= HH) continue;              // wave-uniform
            const int w2 = w + dj;
            if (w2 < 0 || w2 >= WW) continue;        // <=2 edge lanes

            const float scale = sqrtf((float)(di * di + dj * dj));
            const float wsv = -acc[s] * scale;

            int offF = 0, offM = 0;                  // compile-time prefixes
#pragma unroll
            for (int m = 0; m < 25; ++m) {
                const int mi = m / 5, mj = m % 5;
                if (mi == 2 && mj == 2) continue;
                const int cm = (HH - (mi < 2 ? 2 - mi : mi - 2)) *
                               (WW - (mj < 2 ? 2 - mj : mj - 2));
                if (m < i * 5 + j) offF += cm;
                if (m < (4 - i) * 5 + (4 - j)) offM += cm;
            }
            const int cww = WW - (dj < 0 ? -dj : dj);
            const int e1 = offF + h * cww + (w - (dj < 0 ? -dj : 0));
            const int e2 = offM + h * cww + (w + (dj < 0 ? dj : 0));

            wsp[bE + e1] = wsv;
            wsp[bE + e2] = wsv;
        }
    }
}

extern "C" void kernel_launch(void* const* d_in, const int* in_sizes, int n_in,
                              void* d_out, int out_size, void* d_ws, size_t ws_size,
                              hipStream_t stream) {
    const float* x = (const float*)d_in[0];
    float* out = (float*)d_out;
    dim3 block(WW);            // one thread per column
    dim3 grid(HH * BB);        // one block per (row, batch)
    shiftgraph_kernel<<<grid, block, 0, stream>>>(x, out);
}